// Round 5
// baseline (284.015 us; speedup 1.0000x reference)
//
#include <hip/hip_runtime.h>

typedef __bf16 bf16;
typedef __attribute__((ext_vector_type(4))) __bf16 bf16x4;
typedef __attribute__((ext_vector_type(8))) __bf16 bf16x8;
typedef __attribute__((ext_vector_type(4))) float f32x4;
typedef __attribute__((ext_vector_type(16))) float f32x16;
typedef unsigned int u32;

#define D_MODEL 1024
#define SEQ_L   2048
#define NHEAD   16
#define HDIM    64
#define MROWS   4096   // B*L

// 1/sqrt(64) * log2(e): folded into Wq/bq so attn can use raw v_exp_f32 (exp2)
#define S_SCALE 0.18033688f

// ---- workspace layout (bf16-element offsets) ----
#define FEAT_OFF  512u
#define WQ_OFF    (FEAT_OFF + 4194304u)
#define WK_OFF    (WQ_OFF + 1048576u)
#define WV_OFF    (WK_OFF + 1048576u)
#define BQ_OFF    (WV_OFF + 1048576u)
#define BK_OFF    (BQ_OFF + 1024u)
#define BV_OFF    (BK_OFF + 1024u)
#define Q_OFF     (BV_OFF + 1024u)
#define K_OFF     (Q_OFF + 4194304u)
#define V_OFF     (K_OFF + 4194304u)     // z=2 writes Vt here: [b][dout(1024)][token(2048)]
// After qkv_gemm, FEAT/W regions are dead -> reused by attention partials:
//   O1 (bf16, 4096x1024) at FEAT_OFF ; L (f32 [2][32][2048]) at WQ_OFF

// async global->LDS, 16B per lane; LDS dest = wave-uniform base + lane*16
typedef const __attribute__((address_space(1))) u32* gp_t;
typedef __attribute__((address_space(3))) u32* lp_t;
__device__ __forceinline__ void ld16(const bf16* g, bf16* l) {
    __builtin_amdgcn_global_load_lds((gp_t)g, (lp_t)l, 16, 0, 0);
}

// ---------------------------------------------------------------------------
// Convert f32 inputs -> bf16 in ws. Wq/bq pre-scaled by S_SCALE (exact-count
// rounding: one f32->bf16 round either way). Flat grid: 7171 x 256 x 4.
// ---------------------------------------------------------------------------
__global__ void convert_in(const float* __restrict__ feat,
                           const float* __restrict__ wq, const float* __restrict__ wk,
                           const float* __restrict__ wv,
                           const float* __restrict__ bq, const float* __restrict__ bk,
                           const float* __restrict__ bv,
                           bf16* __restrict__ ws) {
    const int bid = blockIdx.x;
    const float* src; bf16* dst; int off; float sc = 1.0f;
    if (bid < 4096)      { src = feat; dst = ws + FEAT_OFF; off = bid * 1024; }
    else if (bid < 5120) { src = wq;   dst = ws + WQ_OFF;   off = (bid - 4096) * 1024; sc = S_SCALE; }
    else if (bid < 6144) { src = wk;   dst = ws + WK_OFF;   off = (bid - 5120) * 1024; }
    else if (bid < 7168) { src = wv;   dst = ws + WV_OFF;   off = (bid - 6144) * 1024; }
    else if (bid == 7168){ src = bq;   dst = ws + BQ_OFF;   off = 0; sc = S_SCALE; }
    else if (bid == 7169){ src = bk;   dst = ws + BK_OFF;   off = 0; }
    else                 { src = bv;   dst = ws + BV_OFF;   off = 0; }
    int idx = off + threadIdx.x * 4;
    float4 v = *(const float4*)(src + idx);
    bf16x4 o;
    o[0] = (bf16)(v.x * sc);
    o[1] = (bf16)(v.y * sc);
    o[2] = (bf16)(v.z * sc);
    o[3] = (bf16)(v.w * sc);
    *(bf16x4*)(dst + idx) = o;          // one 8B store (coalesced)
}

// ---------------------------------------------------------------------------
// QKV projection, m97 recipe. z=0: Q=X*Wq'^T (Wq pre-scaled)  z=1: K=X*Wk^T
// (masked rows ZEROED)  z=2: Vt = Wv*X^T transposed (masked cols ZEROED).
// ---------------------------------------------------------------------------
__global__ __launch_bounds__(256, 2) void qkv_gemm(const bf16* __restrict__ ws,
                                                   bf16* __restrict__ wsw,
                                                   const int* __restrict__ mask) {
    const int zi = blockIdx.z;
    const bf16* Amat = (zi == 2) ? ws + WV_OFF : ws + FEAT_OFF;
    const bf16* Bmat = (zi == 0) ? ws + WQ_OFF : (zi == 1) ? ws + WK_OFF : ws + FEAT_OFF;
    const bf16* bias = ws + ((zi == 0) ? BQ_OFF : (zi == 1) ? BK_OFF : BV_OFF);
    bf16* Y = (zi == 2) ? wsw + V_OFF : wsw + Q_OFF + (size_t)zi * 4194304u;

    __shared__ bf16 Alds[128 * 64];
    __shared__ bf16 Blds[128 * 64];

    const int t    = threadIdx.x;
    const int lane = t & 63;
    const int wave = t >> 6;
    const int quad = lane >> 4;
    const int l16  = lane & 15;
    const int m0   = ((zi == 2) ? blockIdx.y : blockIdx.x) * 128;
    const int n0   = ((zi == 2) ? blockIdx.x : blockIdx.y) * 128;
    const int wrow = (wave >> 1) * 64;
    const int wcol = (wave & 1) * 64;

    const int r8 = lane >> 3;
    const int sl = lane & 7;
    const int sg = sl ^ r8;

    f32x4 acc[4][4];
    for (int mi = 0; mi < 4; ++mi)
        for (int ni = 0; ni < 4; ++ni)
            acc[mi][ni] = (f32x4){0.f, 0.f, 0.f, 0.f};

    for (int k0 = 0; k0 < D_MODEL; k0 += 64) {
#pragma unroll
        for (int i = 0; i < 4; ++i) {
            int ch  = wave * 4 + i;
            int row = ch * 8 + r8;
            ld16(Amat + (size_t)(m0 + row) * D_MODEL + k0 + sg * 8, Alds + ch * 512);
            ld16(Bmat + (size_t)(n0 + row) * D_MODEL + k0 + sg * 8, Blds + ch * 512);
        }
        __syncthreads();

#pragma unroll
        for (int kk = 0; kk < 2; ++kk) {
            const int sgb = quad + kk * 4;
            bf16x8 af[4], bfr[4];
#pragma unroll
            for (int mi = 0; mi < 4; ++mi) {
                int row = wrow + mi * 16 + l16;
                af[mi] = *(const bf16x8*)(&Alds[row * 64 + ((sgb ^ (row & 7)) << 3)]);
            }
#pragma unroll
            for (int ni = 0; ni < 4; ++ni) {
                int row = wcol + ni * 16 + l16;
                bfr[ni] = *(const bf16x8*)(&Blds[row * 64 + ((sgb ^ (row & 7)) << 3)]);
            }
#pragma unroll
            for (int mi = 0; mi < 4; ++mi)
#pragma unroll
                for (int ni = 0; ni < 4; ++ni)
                    acc[mi][ni] = __builtin_amdgcn_mfma_f32_16x16x32_bf16(
                        af[mi], bfr[ni], acc[mi][ni], 0, 0, 0);
        }
        __syncthreads();
    }

    if (zi < 2) {
#pragma unroll
        for (int ni = 0; ni < 4; ++ni) {
            int col = n0 + wcol + ni * 16 + l16;
            float bvf = (float)bias[col];
#pragma unroll
            for (int mi = 0; mi < 4; ++mi) {
                int rowb = m0 + wrow + mi * 16 + quad * 4;
#pragma unroll
                for (int r = 0; r < 4; ++r) {
                    float v = acc[mi][ni][r] + bvf;
                    if (zi == 1 && mask[rowb + r] == 0) v = 0.f;   // zero masked K rows
                    Y[(size_t)(rowb + r) * D_MODEL + col] = (bf16)v;
                }
            }
        }
    } else {
#pragma unroll
        for (int mi = 0; mi < 4; ++mi) {
#pragma unroll
            for (int r = 0; r < 4; ++r) {
                int rowv = m0 + wrow + mi * 16 + quad * 4 + r;   // dout
                float bvf = (float)bias[rowv];
#pragma unroll
                for (int ni = 0; ni < 4; ++ni) {
                    int col = n0 + wcol + ni * 16 + l16;          // token
                    float v = acc[mi][ni][r] + bvf;
                    if (mask[col] == 0) v = 0.f;                  // zero masked Vt cols
                    size_t addr = (size_t)(col >> 11) * 2097152u +
                                  (size_t)rowv * 2048u + (col & 2047);
                    Y[addr] = (bf16)v;
                }
            }
        }
    }
}

// ---------------------------------------------------------------------------
// softmax+pack (v9 numerics): P = exp2(S^T), bf16 pack, C->A layout exchange
// via one shfl_xor(32) per fragment component.
// ---------------------------------------------------------------------------
__device__ __forceinline__ void softmax_pack(const f32x16* st, bf16x8* pf,
                                             const int half) {
    bf16x4 pk[2][4];
#pragma unroll
    for (int ktile = 0; ktile < 2; ++ktile)
#pragma unroll
        for (int g = 0; g < 4; ++g) {
            bf16x4 pkv;
#pragma unroll
            for (int j = 0; j < 4; ++j)
                pkv[j] = (bf16)__builtin_amdgcn_exp2f(st[ktile][g * 4 + j]);
            pk[ktile][g] = pkv;
        }
#pragma unroll
    for (int ks = 0; ks < 4; ++ks) {
        const int k1 = ks & 1, kt2 = ks >> 1;
        uint2 a  = __builtin_bit_cast(uint2, pk[kt2][2 * k1]);
        uint2 bb = __builtin_bit_cast(uint2, pk[kt2][2 * k1 + 1]);
        uint2 keep, send;
        keep.x = half ? bb.x : a.x;  keep.y = half ? bb.y : a.y;
        send.x = half ? a.x : bb.x;  send.y = half ? a.y : bb.y;
        uint2 recv;
        recv.x = (unsigned)__shfl_xor((int)send.x, 32);
        recv.y = (unsigned)__shfl_xor((int)send.y, 32);
        uint4 frag;
        frag.x = half ? recv.x : keep.x;
        frag.y = half ? recv.y : keep.y;
        frag.z = half ? keep.x : recv.x;
        frag.w = half ? keep.y : recv.y;
        pf[ks] = __builtin_bit_cast(bf16x8, frag);
    }
}

// ---------------------------------------------------------------------------
// Flash attention v13 = v9 (the 50.1us best) + cross-iteration MFMA/VALU
// pipelining (T15 mechanism) with a SINGLE st register set:
//   per iter t:  STAGE_K(t+2) ; STAGE_V(t+1)          (async, in flight)
//                softmax(t)   [VALU, consumes st]
//                QK(t+1)      [MFMA, REFILLS st from Klds(t+1)]
//                PV(t)+l(t)   [MFMA, uses pf + Vlds(t)]
//                __syncthreads  (joins + drains prefetch)
// softmax(t+1) at the next iteration start overlaps PV(t)'s still-retiring
// MFMAs -> MFMA||VALU overlap each iter (v9 ran them strictly serial: pipes
// summed to ~36us of 50us wall with no overlap). K is staged 2 tiles ahead
// (3 buffers), V 1 ahead (2 buffers): 40KB LDS -> still 4 blocks/CU,
// 16 waves/CU. Every buffer has >=1 barrier between last-read & overwrite.
// Operations per tile are bitwise-identical to v9.
// grid (bh, qt, ks2) = (32, 16, 2), 256 threads.
// ---------------------------------------------------------------------------
__global__ __launch_bounds__(256, 4) void attn_kernel(
    const bf16* __restrict__ ws, bf16* __restrict__ wsw,
    const int* __restrict__ mask, float* __restrict__ out) {
    const int bh  = blockIdx.x;          // 0..31
    const int qt  = blockIdx.y;          // 0..15 (128 q-rows per block)
    const int ks2 = blockIdx.z;          // key split 0/1
    const int b   = bh >> 4, h = bh & 15;
    const int tid  = threadIdx.x;
    const int lane = tid & 63;
    const int wave = tid >> 6;          // 0..3
    const int half = lane >> 5;
    const int l31  = lane & 31;
    const int kt0  = ks2 * 1024;

    __shared__ bf16 Klds[3][64 * 64];         // [buf][key][d], seg-swizzled
    __shared__ bf16 Vlds[2][64 * 64];         // [buf][d][key], seg-swizzled

    const bf16* Qh  = ws + Q_OFF + (size_t)(b * SEQ_L) * D_MODEL + h * HDIM;
    const bf16* Kh  = ws + K_OFF + (size_t)(b * SEQ_L) * D_MODEL + h * HDIM;
    const bf16* Vth = ws + V_OFF + (size_t)b * 2097152u + (size_t)(h * HDIM) * SEQ_L;

    // staging geometry: wave w, sub i covers rows i*32 + w*8 + (lane>>3)
    const int srow = (lane >> 3);            // 0..7
    const int sg   = (lane & 7) ^ srow;      // swizzled global segment

#define STAGE_K(bb, kt)                                                        \
    do {                                                                       \
        _Pragma("unroll")                                                      \
        for (int i = 0; i < 2; ++i) {                                          \
            int row = i * 32 + wave * 8 + srow;                                \
            ld16(Kh + (size_t)((kt) + row) * D_MODEL + sg * 8,                 \
                 &Klds[bb][i * 2048 + wave * 512]);                            \
        }                                                                      \
    } while (0)
#define STAGE_V(bb, kt)                                                        \
    do {                                                                       \
        _Pragma("unroll")                                                      \
        for (int i = 0; i < 2; ++i) {                                          \
            int row = i * 32 + wave * 8 + srow;                                \
            ld16(Vth + (size_t)row * SEQ_L + (kt) + sg * 8,                    \
                 &Vlds[bb][i * 2048 + wave * 512]);                            \
        }                                                                      \
    } while (0)

    // prologue: K tiles 0,1 and V tile 0
    STAGE_K(0, kt0);
    STAGE_K(1, kt0 + 64);
    STAGE_V(0, kt0);

    // masked-key overcount, hoisted (tile-order independent: masked K rows
    // are zeroed -> each contributes exactly exp2(0)=1 per tile)
    int nm = 0;
    {
        int mvv[16];
#pragma unroll
        for (int i = 0; i < 16; ++i)
            mvv[i] = mask[b * SEQ_L + kt0 + i * 64 + lane];
#pragma unroll
        for (int i = 0; i < 16; ++i)
            nm += (int)__popcll(__ballot(mvv[i] != 0));
    }

    // Q fragments as B-operand (n=q=l31, k=d); scale already folded into Wq.
    const int qrow0 = qt * 128 + wave * 32;
    bf16x8 qf[4];
#pragma unroll
    for (int ks = 0; ks < 4; ++ks)
        qf[ks] = *(const bf16x8*)(Qh + (size_t)(qrow0 + l31) * D_MODEL
                                  + ks * 16 + half * 8);

    bf16x8 ones;
#pragma unroll
    for (int j = 0; j < 8; ++j) ones[j] = (bf16)1.0f;

    f32x16 o[2], lacc;
#pragma unroll
    for (int i = 0; i < 16; ++i) { o[0][i] = 0.f; o[1][i] = 0.f; lacc[i] = 0.f; }

    __syncthreads();    // K0,K1,V0 staged; all waves joined

    // QK(0): S^T = K * Q^T from Klds[0]
    f32x16 st[2];
#pragma unroll
    for (int ktile = 0; ktile < 2; ++ktile) {
#pragma unroll
        for (int i = 0; i < 16; ++i) st[ktile][i] = 0.f;
#pragma unroll
        for (int ks = 0; ks < 4; ++ks) {
            const int row  = ktile * 32 + l31;
            const int slot = (ks * 2 + half) ^ (l31 & 7);
            bf16x8 kf = *(const bf16x8*)(&Klds[0][row * 64 + slot * 8]);
            st[ktile] = __builtin_amdgcn_mfma_f32_32x32x16_bf16(
                kf, qf[ks], st[ktile], 0, 0, 0);
        }
    }

#pragma unroll
    for (int it = 0; it < 16; ++it) {
        const int kt = kt0 + it * 64;
        // ---- async prefetch: K two tiles ahead, V one tile ahead
        if (it < 14) STAGE_K((it + 2) % 3, kt + 128);
        if (it < 15) STAGE_V((it + 1) & 1, kt + 64);

        // ---- softmax(t): consume st -> pf (VALU; overlaps prev iter's PV)
        bf16x8 pf[4];
        softmax_pack(st, pf, half);

        // ---- QK(t+1): refill st from Klds[(it+1)%3] (MFMA)
        if (it < 15) {
#pragma unroll
            for (int ktile = 0; ktile < 2; ++ktile) {
#pragma unroll
                for (int i = 0; i < 16; ++i) st[ktile][i] = 0.f;
#pragma unroll
                for (int ks = 0; ks < 4; ++ks) {
                    const int row  = ktile * 32 + l31;
                    const int slot = (ks * 2 + half) ^ (l31 & 7);
                    bf16x8 kf = *(const bf16x8*)(&Klds[(it + 1) % 3][row * 64 + slot * 8]);
                    st[ktile] = __builtin_amdgcn_mfma_f32_32x32x16_bf16(
                        kf, qf[ks], st[ktile], 0, 0, 0);
                }
            }
        }

        // ---- PV(t): O += P*V ; l += P*ones, from Vlds[it&1]
#pragma unroll
        for (int ks = 0; ks < 4; ++ks)
            lacc = __builtin_amdgcn_mfma_f32_32x32x16_bf16(pf[ks], ones, lacc, 0, 0, 0);
#pragma unroll
        for (int dt = 0; dt < 2; ++dt) {
#pragma unroll
            for (int ks = 0; ks < 4; ++ks) {
                const int row  = dt * 32 + l31;
                const int slot = (ks * 2 + half) ^ (l31 & 7);
                bf16x8 vf = *(const bf16x8*)(&Vlds[it & 1][row * 64 + slot * 8]);
                o[dt] = __builtin_amdgcn_mfma_f32_32x32x16_bf16(
                    pf[ks], vf, o[dt], 0, 0, 0);
            }
        }

        // joins waves AND drains the in-flight prefetch
        __syncthreads();
    }
#undef STAGE_K
#undef STAGE_V

    // ---- export partials; lacc C-layout row = q32 (all cols identical);
    //      subtract masked-key overcount (exact integer)
    float* Lp  = (float*)(wsw + WQ_OFF);          // [2][32][2048]
    bf16*  O1  = wsw + FEAT_OFF;                  // [4096][1024]
    const float corr = (float)(1024 - nm);
#pragma unroll
    for (int r = 0; r < 16; ++r) {
        const int q32 = (r & 3) + 8 * (r >> 2) + 4 * half;
        const int q = qrow0 + q32;
        const size_t base = ((size_t)(b * SEQ_L + q)) * D_MODEL + h * HDIM;
        if (l31 == 0)
            Lp[ks2 * 65536 + bh * 2048 + qrow0 + q32] = lacc[r] - corr;
        if (ks2 == 0) {
            out[base + l31]      = o[0][r];
            out[base + 32 + l31] = o[1][r];
        } else {
            O1[base + l31]      = (bf16)o[0][r];
            O1[base + 32 + l31] = (bf16)o[1][r];
        }
    }
}

// ---------------------------------------------------------------------------
// Combine key-split partials: out = (o0 + o1) / (l0 + l1)
// ---------------------------------------------------------------------------
__global__ void combine(float* __restrict__ out, const bf16* __restrict__ ws) {
    const float* Lp = (const float*)(ws + WQ_OFF);
    const bf16*  O1 = ws + FEAT_OFF;
    int idx = (blockIdx.x * 256 + threadIdx.x) * 4;   // over 4096*1024
    int row = idx >> 10;          // b*2048 + q
    int col = idx & 1023;         // h*64 + dh
    int b = row >> 11, q = row & 2047, h = col >> 6;
    int li = (b * 16 + h) * 2048 + q;
    float rl = 1.0f / fmaxf(Lp[li] + Lp[65536 + li], 1e-30f);
    float4 o0 = *(float4*)(out + idx);
    bf16x4 o1 = *(const bf16x4*)(O1 + idx);
    float4 res;
    res.x = (o0.x + (float)o1[0]) * rl;
    res.y = (o0.y + (float)o1[1]) * rl;
    res.z = (o0.z + (float)o1[2]) * rl;
    res.w = (o0.w + (float)o1[3]) * rl;
    *(float4*)(out + idx) = res;
}

extern "C" void kernel_launch(void* const* d_in, const int* in_sizes, int n_in,
                              void* d_out, int out_size, void* d_ws, size_t ws_size,
                              hipStream_t stream) {
    const float* feat = (const float*)d_in[0];
    const int*   mask = (const int*)d_in[1];
    const float* Wq = (const float*)d_in[2];
    const float* bq = (const float*)d_in[3];
    const float* Wk = (const float*)d_in[4];
    const float* bk = (const float*)d_in[5];
    const float* Wv = (const float*)d_in[6];
    const float* bv = (const float*)d_in[7];

    bf16* ws = (bf16*)d_ws;

    convert_in<<<7171, 256, 0, stream>>>(feat, Wq, Wk, Wv, bq, bk, bv, ws);

    dim3 g1(32, 8, 3);
    qkv_gemm<<<g1, 256, 0, stream>>>(ws, ws, mask);

    dim3 g2(2 * NHEAD, SEQ_L / 128, 2);
    attn_kernel<<<g2, 256, 0, stream>>>(ws, ws, mask, (float*)d_out);

    combine<<<4096, 256, 0, stream>>>((float*)d_out, ws);
}

// Round 6
// 176.047 us; speedup vs baseline: 1.6133x; 1.6133x over previous
//
#include <hip/hip_runtime.h>

typedef __bf16 bf16;
typedef __attribute__((ext_vector_type(4))) __bf16 bf16x4;
typedef __attribute__((ext_vector_type(8))) __bf16 bf16x8;
typedef __attribute__((ext_vector_type(4))) float f32x4;
typedef __attribute__((ext_vector_type(16))) float f32x16;
typedef unsigned int u32;

#define D_MODEL 1024
#define SEQ_L   2048
#define NHEAD   16
#define HDIM    64
#define MROWS   4096   // B*L

// 1/sqrt(64) * log2(e): folded into Wq/bq so attn can use raw v_exp_f32 (exp2)
#define S_SCALE 0.18033688f

// ---- workspace layout (bf16-element offsets) ----
#define FEAT_OFF  512u
#define WQ_OFF    (FEAT_OFF + 4194304u)
#define WK_OFF    (WQ_OFF + 1048576u)
#define WV_OFF    (WK_OFF + 1048576u)
#define BQ_OFF    (WV_OFF + 1048576u)
#define BK_OFF    (BQ_OFF + 1024u)
#define BV_OFF    (BK_OFF + 1024u)
#define Q_OFF     (BV_OFF + 1024u)
#define K_OFF     (Q_OFF + 4194304u)
#define V_OFF     (K_OFF + 4194304u)     // z=2 writes Vt here: [b][dout(1024)][token(2048)]
// After qkv_gemm, FEAT/W regions are dead -> reused by attention partials:
//   O1 (bf16, 4096x1024) at FEAT_OFF ; L (f32 [2][32][2048]) at WQ_OFF

// async global->LDS, 16B per lane; LDS dest = wave-uniform base + lane*16
typedef const __attribute__((address_space(1))) u32* gp_t;
typedef __attribute__((address_space(3))) u32* lp_t;
__device__ __forceinline__ void ld16(const bf16* g, bf16* l) {
    __builtin_amdgcn_global_load_lds((gp_t)g, (lp_t)l, 16, 0, 0);
}

// ---------------------------------------------------------------------------
// Convert f32 inputs -> bf16 in ws. Wq/bq pre-scaled by S_SCALE (exact-count
// rounding: one f32->bf16 round either way). Flat grid: 7171 x 256 x 4.
// ---------------------------------------------------------------------------
__global__ void convert_in(const float* __restrict__ feat,
                           const float* __restrict__ wq, const float* __restrict__ wk,
                           const float* __restrict__ wv,
                           const float* __restrict__ bq, const float* __restrict__ bk,
                           const float* __restrict__ bv,
                           bf16* __restrict__ ws) {
    const int bid = blockIdx.x;
    const float* src; bf16* dst; int off; float sc = 1.0f;
    if (bid < 4096)      { src = feat; dst = ws + FEAT_OFF; off = bid * 1024; }
    else if (bid < 5120) { src = wq;   dst = ws + WQ_OFF;   off = (bid - 4096) * 1024; sc = S_SCALE; }
    else if (bid < 6144) { src = wk;   dst = ws + WK_OFF;   off = (bid - 5120) * 1024; }
    else if (bid < 7168) { src = wv;   dst = ws + WV_OFF;   off = (bid - 6144) * 1024; }
    else if (bid == 7168){ src = bq;   dst = ws + BQ_OFF;   off = 0; sc = S_SCALE; }
    else if (bid == 7169){ src = bk;   dst = ws + BK_OFF;   off = 0; }
    else                 { src = bv;   dst = ws + BV_OFF;   off = 0; }
    int idx = off + threadIdx.x * 4;
    float4 v = *(const float4*)(src + idx);
    bf16x4 o;
    o[0] = (bf16)(v.x * sc);
    o[1] = (bf16)(v.y * sc);
    o[2] = (bf16)(v.z * sc);
    o[3] = (bf16)(v.w * sc);
    *(bf16x4*)(dst + idx) = o;          // one 8B store (coalesced)
}

// ---------------------------------------------------------------------------
// QKV projection, m97 recipe. z=0: Q=X*Wq'^T (Wq pre-scaled)  z=1: K=X*Wk^T
// (masked rows ZEROED)  z=2: Vt = Wv*X^T transposed (masked cols ZEROED).
// launch_bounds(256,3): 3 blocks/CU -> all 768 blocks co-resident in ONE
// round (at (256,2) the grid ran as 512 + 256, a half-empty tail round).
// VGPR cap 170 >= the ~160 this structure needs (m97-analog: 164).
// ---------------------------------------------------------------------------
__global__ __launch_bounds__(256, 3) void qkv_gemm(const bf16* __restrict__ ws,
                                                   bf16* __restrict__ wsw,
                                                   const int* __restrict__ mask) {
    const int zi = blockIdx.z;
    const bf16* Amat = (zi == 2) ? ws + WV_OFF : ws + FEAT_OFF;
    const bf16* Bmat = (zi == 0) ? ws + WQ_OFF : (zi == 1) ? ws + WK_OFF : ws + FEAT_OFF;
    const bf16* bias = ws + ((zi == 0) ? BQ_OFF : (zi == 1) ? BK_OFF : BV_OFF);
    bf16* Y = (zi == 2) ? wsw + V_OFF : wsw + Q_OFF + (size_t)zi * 4194304u;

    __shared__ bf16 Alds[128 * 64];
    __shared__ bf16 Blds[128 * 64];

    const int t    = threadIdx.x;
    const int lane = t & 63;
    const int wave = t >> 6;
    const int quad = lane >> 4;
    const int l16  = lane & 15;
    const int m0   = ((zi == 2) ? blockIdx.y : blockIdx.x) * 128;
    const int n0   = ((zi == 2) ? blockIdx.x : blockIdx.y) * 128;
    const int wrow = (wave >> 1) * 64;
    const int wcol = (wave & 1) * 64;

    const int r8 = lane >> 3;
    const int sl = lane & 7;
    const int sg = sl ^ r8;

    f32x4 acc[4][4];
    for (int mi = 0; mi < 4; ++mi)
        for (int ni = 0; ni < 4; ++ni)
            acc[mi][ni] = (f32x4){0.f, 0.f, 0.f, 0.f};

    for (int k0 = 0; k0 < D_MODEL; k0 += 64) {
#pragma unroll
        for (int i = 0; i < 4; ++i) {
            int ch  = wave * 4 + i;
            int row = ch * 8 + r8;
            ld16(Amat + (size_t)(m0 + row) * D_MODEL + k0 + sg * 8, Alds + ch * 512);
            ld16(Bmat + (size_t)(n0 + row) * D_MODEL + k0 + sg * 8, Blds + ch * 512);
        }
        __syncthreads();

#pragma unroll
        for (int kk = 0; kk < 2; ++kk) {
            const int sgb = quad + kk * 4;
            bf16x8 af[4], bfr[4];
#pragma unroll
            for (int mi = 0; mi < 4; ++mi) {
                int row = wrow + mi * 16 + l16;
                af[mi] = *(const bf16x8*)(&Alds[row * 64 + ((sgb ^ (row & 7)) << 3)]);
            }
#pragma unroll
            for (int ni = 0; ni < 4; ++ni) {
                int row = wcol + ni * 16 + l16;
                bfr[ni] = *(const bf16x8*)(&Blds[row * 64 + ((sgb ^ (row & 7)) << 3)]);
            }
#pragma unroll
            for (int mi = 0; mi < 4; ++mi)
#pragma unroll
                for (int ni = 0; ni < 4; ++ni)
                    acc[mi][ni] = __builtin_amdgcn_mfma_f32_16x16x32_bf16(
                        af[mi], bfr[ni], acc[mi][ni], 0, 0, 0);
        }
        __syncthreads();
    }

    if (zi < 2) {
#pragma unroll
        for (int ni = 0; ni < 4; ++ni) {
            int col = n0 + wcol + ni * 16 + l16;
            float bvf = (float)bias[col];
#pragma unroll
            for (int mi = 0; mi < 4; ++mi) {
                int rowb = m0 + wrow + mi * 16 + quad * 4;
#pragma unroll
                for (int r = 0; r < 4; ++r) {
                    float v = acc[mi][ni][r] + bvf;
                    if (zi == 1 && mask[rowb + r] == 0) v = 0.f;   // zero masked K rows
                    Y[(size_t)(rowb + r) * D_MODEL + col] = (bf16)v;
                }
            }
        }
    } else {
#pragma unroll
        for (int mi = 0; mi < 4; ++mi) {
#pragma unroll
            for (int r = 0; r < 4; ++r) {
                int rowv = m0 + wrow + mi * 16 + quad * 4 + r;   // dout
                float bvf = (float)bias[rowv];
#pragma unroll
                for (int ni = 0; ni < 4; ++ni) {
                    int col = n0 + wcol + ni * 16 + l16;          // token
                    float v = acc[mi][ni][r] + bvf;
                    if (mask[col] == 0) v = 0.f;                  // zero masked Vt cols
                    size_t addr = (size_t)(col >> 11) * 2097152u +
                                  (size_t)rowv * 2048u + (col & 2047);
                    Y[addr] = (bf16)v;
                }
            }
        }
    }
}

// ---------------------------------------------------------------------------
// Flash attention v9 (RESTORED VERBATIM — best measured: 50.1us attn, 173.6us
// total). Rounds 2-5 tested: more per-wave ILP (v10, -occupancy, neutral),
// hoisted mask (v11, neutral), no-LDS direct-global (v12, latency death,
// 128us), cross-iter MFMA/VALU pipelining (v13, VGPR spill catastrophe,
// 165us+). Conclusion: this structure's ~50us is convoy/chain-bound and
// every source-level overlap attempt loses more than it gains. Keep v9.
// grid (bh, qt, ks2) = (32, 16, 2), 256 thr, 4 waves, 2-phase K/V prefetch.
// ---------------------------------------------------------------------------
__global__ __launch_bounds__(256, 4) void attn_kernel(
    const bf16* __restrict__ ws, bf16* __restrict__ wsw,
    const int* __restrict__ mask, float* __restrict__ out) {
    const int bh  = blockIdx.x;          // 0..31
    const int qt  = blockIdx.y;          // 0..15 (128 q-rows per block)
    const int ks2 = blockIdx.z;          // key split 0/1
    const int b   = bh >> 4, h = bh & 15;
    const int t    = threadIdx.x;
    const int lane = t & 63;
    const int wave = t >> 6;            // 0..3
    const int half = lane >> 5;
    const int l31  = lane & 31;
    const int kt0  = ks2 * 1024;

    __shared__ bf16 Klds[2][64 * 64];         // [buf][key][d], seg-swizzled
    __shared__ bf16 Vlds[2][64 * 64];         // [buf][d][key], seg-swizzled

    const bf16* Qh  = ws + Q_OFF + (size_t)(b * SEQ_L) * D_MODEL + h * HDIM;
    const bf16* Kh  = ws + K_OFF + (size_t)(b * SEQ_L) * D_MODEL + h * HDIM;
    const bf16* Vth = ws + V_OFF + (size_t)b * 2097152u + (size_t)(h * HDIM) * SEQ_L;

    // Q fragments as B-operand (n=q=l31, k=d); scale already folded into Wq.
    const int qrow0 = qt * 128 + wave * 32;
    bf16x8 qf[4];
#pragma unroll
    for (int ks = 0; ks < 4; ++ks)
        qf[ks] = *(const bf16x8*)(Qh + (size_t)(qrow0 + l31) * D_MODEL
                                  + ks * 16 + half * 8);

    bf16x8 ones;
#pragma unroll
    for (int j = 0; j < 8; ++j) ones[j] = (bf16)1.0f;

    f32x16 o[2], lacc;
    int nm = 0;                               // unmasked-key count
#pragma unroll
    for (int i = 0; i < 16; ++i) { o[0][i] = 0.f; o[1][i] = 0.f; lacc[i] = 0.f; }

    // staging geometry: per iter i, wave w covers rows i*32 + w*8 + (lane>>3)
    const int srow = (lane >> 3);            // 0..7
    const int sg   = (lane & 7) ^ srow;      // swizzled global segment

#define STAGE(bb, kt)                                                          \
    do {                                                                       \
        _Pragma("unroll")                                                      \
        for (int i = 0; i < 2; ++i) {                                          \
            int row = i * 32 + wave * 8 + srow;                                \
            ld16(Kh + (size_t)((kt) + row) * D_MODEL + sg * 8,                 \
                 &Klds[bb][i * 2048 + wave * 512]);                            \
            ld16(Vth + (size_t)row * SEQ_L + (kt) + sg * 8,                    \
                 &Vlds[bb][i * 2048 + wave * 512]);                            \
        }                                                                      \
    } while (0)

    // prologue: fill buffer 0
    STAGE(0, kt0);
    __syncthreads();

    int cur = 0;
    for (int kt = kt0; kt < kt0 + 1024; kt += 64) {
        // ---- issue next-tile prefetch FIRST (stays in flight under compute)
        if (kt + 64 < kt0 + 1024) STAGE(cur ^ 1, kt + 64);

        int mv = mask[b * SEQ_L + kt + lane];
        nm += (int)__popcll(__ballot(mv != 0));

        // ---- S^T = K * Q^T : D[key-rows][q-cols]  (Q pre-scaled)
        f32x16 st[2];
#pragma unroll
        for (int ktile = 0; ktile < 2; ++ktile) {
#pragma unroll
            for (int i = 0; i < 16; ++i) st[ktile][i] = 0.f;
#pragma unroll
            for (int ks = 0; ks < 4; ++ks) {
                const int row  = ktile * 32 + l31;
                const int slot = (ks * 2 + half) ^ (l31 & 7);
                bf16x8 kf = *(const bf16x8*)(&Klds[cur][row * 64 + slot * 8]);
                st[ktile] = __builtin_amdgcn_mfma_f32_32x32x16_bf16(
                    kf, qf[ks], st[ktile], 0, 0, 0);
            }
        }

        // ---- P = exp2(S^T); masked keys give st=0 -> p=1 (corrected in l)
        bf16x4 pk[2][4];
#pragma unroll
        for (int ktile = 0; ktile < 2; ++ktile) {
#pragma unroll
            for (int g = 0; g < 4; ++g) {
                bf16x4 pkv;
#pragma unroll
                for (int j = 0; j < 4; ++j)
                    pkv[j] = (bf16)__builtin_amdgcn_exp2f(st[ktile][g * 4 + j]);
                pk[ktile][g] = pkv;
            }
        }

        // ---- C->A layout via one shfl_xor(32) per fragment
        bf16x8 pf[4];
#pragma unroll
        for (int ks = 0; ks < 4; ++ks) {
            const int k1 = ks & 1, kt2 = ks >> 1;
            uint2 a  = __builtin_bit_cast(uint2, pk[kt2][2 * k1]);
            uint2 bb = __builtin_bit_cast(uint2, pk[kt2][2 * k1 + 1]);
            uint2 keep, send;
            keep.x = half ? bb.x : a.x;  keep.y = half ? bb.y : a.y;
            send.x = half ? a.x : bb.x;  send.y = half ? a.y : bb.y;
            uint2 recv;
            recv.x = (unsigned)__shfl_xor((int)send.x, 32);
            recv.y = (unsigned)__shfl_xor((int)send.y, 32);
            uint4 frag;
            frag.x = half ? recv.x : keep.x;
            frag.y = half ? recv.y : keep.y;
            frag.z = half ? keep.x : recv.x;
            frag.w = half ? keep.y : recv.y;
            pf[ks] = __builtin_bit_cast(bf16x8, frag);
        }

        // ---- O += P * V ; l += P * ones (row-sums on the MFMA pipe)
#pragma unroll
        for (int ks = 0; ks < 4; ++ks)
            lacc = __builtin_amdgcn_mfma_f32_32x32x16_bf16(pf[ks], ones, lacc, 0, 0, 0);
#pragma unroll
        for (int dt = 0; dt < 2; ++dt) {
#pragma unroll
            for (int ks = 0; ks < 4; ++ks) {
                const int row  = dt * 32 + l31;
                const int slot = (ks * 2 + half) ^ (l31 & 7);
                bf16x8 vf = *(const bf16x8*)(&Vlds[cur][row * 64 + slot * 8]);
                o[dt] = __builtin_amdgcn_mfma_f32_32x32x16_bf16(
                    pf[ks], vf, o[dt], 0, 0, 0);
            }
        }

        // joins waves AND drains the in-flight prefetch (vmcnt(0) before barrier)
        __syncthreads();
        cur ^= 1;
    }
#undef STAGE

    // ---- export partials; lacc C-layout row = q32 (all cols identical);
    //      subtract masked-key overcount (exact integer)
    float* Lp  = (float*)(wsw + WQ_OFF);          // [2][32][2048]
    bf16*  O1  = wsw + FEAT_OFF;                  // [4096][1024]
    const float corr = (float)(1024 - nm);
#pragma unroll
    for (int r = 0; r < 16; ++r) {
        const int q32 = (r & 3) + 8 * (r >> 2) + 4 * half;
        const int q = qrow0 + q32;
        const size_t base = ((size_t)(b * SEQ_L + q)) * D_MODEL + h * HDIM;
        if (l31 == 0)
            Lp[ks2 * 65536 + bh * 2048 + qrow0 + q32] = lacc[r] - corr;
        if (ks2 == 0) {
            out[base + l31]      = o[0][r];
            out[base + 32 + l31] = o[1][r];
        } else {
            O1[base + l31]      = (bf16)o[0][r];
            O1[base + 32 + l31] = (bf16)o[1][r];
        }
    }
}

// ---------------------------------------------------------------------------
// Combine key-split partials: out = (o0 + o1) / (l0 + l1)
// ---------------------------------------------------------------------------
__global__ void combine(float* __restrict__ out, const bf16* __restrict__ ws) {
    const float* Lp = (const float*)(ws + WQ_OFF);
    const bf16*  O1 = ws + FEAT_OFF;
    int idx = (blockIdx.x * 256 + threadIdx.x) * 4;   // over 4096*1024
    int row = idx >> 10;          // b*2048 + q
    int col = idx & 1023;         // h*64 + dh
    int b = row >> 11, q = row & 2047, h = col >> 6;
    int li = (b * 16 + h) * 2048 + q;
    float rl = 1.0f / fmaxf(Lp[li] + Lp[65536 + li], 1e-30f);
    float4 o0 = *(float4*)(out + idx);
    bf16x4 o1 = *(const bf16x4*)(O1 + idx);
    float4 res;
    res.x = (o0.x + (float)o1[0]) * rl;
    res.y = (o0.y + (float)o1[1]) * rl;
    res.z = (o0.z + (float)o1[2]) * rl;
    res.w = (o0.w + (float)o1[3]) * rl;
    *(float4*)(out + idx) = res;
}

extern "C" void kernel_launch(void* const* d_in, const int* in_sizes, int n_in,
                              void* d_out, int out_size, void* d_ws, size_t ws_size,
                              hipStream_t stream) {
    const float* feat = (const float*)d_in[0];
    const int*   mask = (const int*)d_in[1];
    const float* Wq = (const float*)d_in[2];
    const float* bq = (const float*)d_in[3];
    const float* Wk = (const float*)d_in[4];
    const float* bk = (const float*)d_in[5];
    const float* Wv = (const float*)d_in[6];
    const float* bv = (const float*)d_in[7];

    bf16* ws = (bf16*)d_ws;

    convert_in<<<7171, 256, 0, stream>>>(feat, Wq, Wk, Wv, bq, bk, bv, ws);

    dim3 g1(32, 8, 3);
    qkv_gemm<<<g1, 256, 0, stream>>>(ws, ws, mask);

    dim3 g2(2 * NHEAD, SEQ_L / 128, 2);
    attn_kernel<<<g2, 256, 0, stream>>>(ws, ws, mask, (float*)d_out);

    combine<<<4096, 256, 0, stream>>>((float*)d_out, ws);
}

// Round 7
// 174.612 us; speedup vs baseline: 1.6265x; 1.0082x over previous
//
#include <hip/hip_runtime.h>

typedef __bf16 bf16;
typedef __attribute__((ext_vector_type(4))) __bf16 bf16x4;
typedef __attribute__((ext_vector_type(8))) __bf16 bf16x8;
typedef __attribute__((ext_vector_type(4))) float f32x4;
typedef __attribute__((ext_vector_type(16))) float f32x16;
typedef unsigned int u32;

#define D_MODEL 1024
#define SEQ_L   2048
#define NHEAD   16
#define HDIM    64
#define MROWS   4096   // B*L

// 1/sqrt(64) * log2(e): folded into Wq/bq so attn can use raw v_exp_f32 (exp2)
#define S_SCALE 0.18033688f

// ---- workspace layout (bf16-element offsets) ----
#define FEAT_OFF  512u
#define WQ_OFF    (FEAT_OFF + 4194304u)
#define WK_OFF    (WQ_OFF + 1048576u)
#define WV_OFF    (WK_OFF + 1048576u)
#define BQ_OFF    (WV_OFF + 1048576u)
#define BK_OFF    (BQ_OFF + 1024u)
#define BV_OFF    (BK_OFF + 1024u)
#define Q_OFF     (BV_OFF + 1024u)
#define K_OFF     (Q_OFF + 4194304u)
#define V_OFF     (K_OFF + 4194304u)     // z=2 writes Vt here: [b][dout(1024)][token(2048)]

// async global->LDS, 16B per lane; LDS dest = wave-uniform base + lane*16
typedef const __attribute__((address_space(1))) u32* gp_t;
typedef __attribute__((address_space(3))) u32* lp_t;
__device__ __forceinline__ void ld16(const bf16* g, bf16* l) {
    __builtin_amdgcn_global_load_lds((gp_t)g, (lp_t)l, 16, 0, 0);
}

// ---------------------------------------------------------------------------
// Convert f32 inputs -> bf16 in ws. Wq/bq pre-scaled by S_SCALE (exact-count
// rounding: one f32->bf16 round either way). Flat grid: 7171 x 256 x 4.
// ---------------------------------------------------------------------------
__global__ void convert_in(const float* __restrict__ feat,
                           const float* __restrict__ wq, const float* __restrict__ wk,
                           const float* __restrict__ wv,
                           const float* __restrict__ bq, const float* __restrict__ bk,
                           const float* __restrict__ bv,
                           bf16* __restrict__ ws) {
    const int bid = blockIdx.x;
    const float* src; bf16* dst; int off; float sc = 1.0f;
    if (bid < 4096)      { src = feat; dst = ws + FEAT_OFF; off = bid * 1024; }
    else if (bid < 5120) { src = wq;   dst = ws + WQ_OFF;   off = (bid - 4096) * 1024; sc = S_SCALE; }
    else if (bid < 6144) { src = wk;   dst = ws + WK_OFF;   off = (bid - 5120) * 1024; }
    else if (bid < 7168) { src = wv;   dst = ws + WV_OFF;   off = (bid - 6144) * 1024; }
    else if (bid == 7168){ src = bq;   dst = ws + BQ_OFF;   off = 0; sc = S_SCALE; }
    else if (bid == 7169){ src = bk;   dst = ws + BK_OFF;   off = 0; }
    else                 { src = bv;   dst = ws + BV_OFF;   off = 0; }
    int idx = off + threadIdx.x * 4;
    float4 v = *(const float4*)(src + idx);
    bf16x4 o;
    o[0] = (bf16)(v.x * sc);
    o[1] = (bf16)(v.y * sc);
    o[2] = (bf16)(v.z * sc);
    o[3] = (bf16)(v.w * sc);
    *(bf16x4*)(dst + idx) = o;          // one 8B store (coalesced)
}

// ---------------------------------------------------------------------------
// QKV projection, m97 recipe. z=0: Q=X*Wq'^T (Wq pre-scaled)  z=1: K=X*Wk^T
// (masked rows ZEROED)  z=2: Vt = Wv*X^T transposed (masked cols ZEROED).
// launch_bounds(256,2) — round-6 tested (256,3): neutral-to-worse; reverted.
// ---------------------------------------------------------------------------
__global__ __launch_bounds__(256, 2) void qkv_gemm(const bf16* __restrict__ ws,
                                                   bf16* __restrict__ wsw,
                                                   const int* __restrict__ mask) {
    const int zi = blockIdx.z;
    const bf16* Amat = (zi == 2) ? ws + WV_OFF : ws + FEAT_OFF;
    const bf16* Bmat = (zi == 0) ? ws + WQ_OFF : (zi == 1) ? ws + WK_OFF : ws + FEAT_OFF;
    const bf16* bias = ws + ((zi == 0) ? BQ_OFF : (zi == 1) ? BK_OFF : BV_OFF);
    bf16* Y = (zi == 2) ? wsw + V_OFF : wsw + Q_OFF + (size_t)zi * 4194304u;

    __shared__ bf16 Alds[128 * 64];
    __shared__ bf16 Blds[128 * 64];

    const int t    = threadIdx.x;
    const int lane = t & 63;
    const int wave = t >> 6;
    const int quad = lane >> 4;
    const int l16  = lane & 15;
    const int m0   = ((zi == 2) ? blockIdx.y : blockIdx.x) * 128;
    const int n0   = ((zi == 2) ? blockIdx.x : blockIdx.y) * 128;
    const int wrow = (wave >> 1) * 64;
    const int wcol = (wave & 1) * 64;

    const int r8 = lane >> 3;
    const int sl = lane & 7;
    const int sg = sl ^ r8;

    f32x4 acc[4][4];
    for (int mi = 0; mi < 4; ++mi)
        for (int ni = 0; ni < 4; ++ni)
            acc[mi][ni] = (f32x4){0.f, 0.f, 0.f, 0.f};

    for (int k0 = 0; k0 < D_MODEL; k0 += 64) {
#pragma unroll
        for (int i = 0; i < 4; ++i) {
            int ch  = wave * 4 + i;
            int row = ch * 8 + r8;
            ld16(Amat + (size_t)(m0 + row) * D_MODEL + k0 + sg * 8, Alds + ch * 512);
            ld16(Bmat + (size_t)(n0 + row) * D_MODEL + k0 + sg * 8, Blds + ch * 512);
        }
        __syncthreads();

#pragma unroll
        for (int kk = 0; kk < 2; ++kk) {
            const int sgb = quad + kk * 4;
            bf16x8 af[4], bfr[4];
#pragma unroll
            for (int mi = 0; mi < 4; ++mi) {
                int row = wrow + mi * 16 + l16;
                af[mi] = *(const bf16x8*)(&Alds[row * 64 + ((sgb ^ (row & 7)) << 3)]);
            }
#pragma unroll
            for (int ni = 0; ni < 4; ++ni) {
                int row = wcol + ni * 16 + l16;
                bfr[ni] = *(const bf16x8*)(&Blds[row * 64 + ((sgb ^ (row & 7)) << 3)]);
            }
#pragma unroll
            for (int mi = 0; mi < 4; ++mi)
#pragma unroll
                for (int ni = 0; ni < 4; ++ni)
                    acc[mi][ni] = __builtin_amdgcn_mfma_f32_16x16x32_bf16(
                        af[mi], bfr[ni], acc[mi][ni], 0, 0, 0);
        }
        __syncthreads();
    }

    if (zi < 2) {
#pragma unroll
        for (int ni = 0; ni < 4; ++ni) {
            int col = n0 + wcol + ni * 16 + l16;
            float bvf = (float)bias[col];
#pragma unroll
            for (int mi = 0; mi < 4; ++mi) {
                int rowb = m0 + wrow + mi * 16 + quad * 4;
#pragma unroll
                for (int r = 0; r < 4; ++r) {
                    float v = acc[mi][ni][r] + bvf;
                    if (zi == 1 && mask[rowb + r] == 0) v = 0.f;   // zero masked K rows
                    Y[(size_t)(rowb + r) * D_MODEL + col] = (bf16)v;
                }
            }
        }
    } else {
#pragma unroll
        for (int mi = 0; mi < 4; ++mi) {
#pragma unroll
            for (int r = 0; r < 4; ++r) {
                int rowv = m0 + wrow + mi * 16 + quad * 4 + r;   // dout
                float bvf = (float)bias[rowv];
#pragma unroll
                for (int ni = 0; ni < 4; ++ni) {
                    int col = n0 + wcol + ni * 16 + l16;          // token
                    float v = acc[mi][ni][r] + bvf;
                    if (mask[col] == 0) v = 0.f;                  // zero masked Vt cols
                    size_t addr = (size_t)(col >> 11) * 2097152u +
                                  (size_t)rowv * 2048u + (col & 2047);
                    Y[addr] = (bf16)v;
                }
            }
        }
    }
}

// ---------------------------------------------------------------------------
// Flash attention v14 = v9 structure (best measured) WITHOUT the key-split:
// each block sweeps all 2048 keys (32 iters). Normalization is free
// in-register: lacc[r] (P*ones row-sum) is column-replicated per lane, so the
// epilogue does o[dt][r] * 1/(lacc[r]-corr) and writes FINAL f32 directly.
// Deletes the combine kernel (40 MB traffic + a launch) and the O1/Lp
// partial writes (25 MB -> 16.8 MB). Occupancy drops 16 -> 8 waves/CU, which
// rounds 1-3 showed costs only ~1.5us in this convoy-bound regime.
// grid (bh, qt) = (32, 16), 256 thr, 4 waves, 2-phase K/V prefetch.
// ---------------------------------------------------------------------------
__global__ __launch_bounds__(256, 4) void attn_kernel(
    const bf16* __restrict__ ws,
    const int* __restrict__ mask, float* __restrict__ out) {
    const int bh  = blockIdx.x;          // 0..31
    const int qt  = blockIdx.y;          // 0..15 (128 q-rows per block)
    const int b   = bh >> 4, h = bh & 15;
    const int t    = threadIdx.x;
    const int lane = t & 63;
    const int wave = t >> 6;            // 0..3
    const int half = lane >> 5;
    const int l31  = lane & 31;

    __shared__ bf16 Klds[2][64 * 64];         // [buf][key][d], seg-swizzled
    __shared__ bf16 Vlds[2][64 * 64];         // [buf][d][key], seg-swizzled

    const bf16* Qh  = ws + Q_OFF + (size_t)(b * SEQ_L) * D_MODEL + h * HDIM;
    const bf16* Kh  = ws + K_OFF + (size_t)(b * SEQ_L) * D_MODEL + h * HDIM;
    const bf16* Vth = ws + V_OFF + (size_t)b * 2097152u + (size_t)(h * HDIM) * SEQ_L;

    // Q fragments as B-operand (n=q=l31, k=d); scale already folded into Wq.
    const int qrow0 = qt * 128 + wave * 32;
    bf16x8 qf[4];
#pragma unroll
    for (int ks = 0; ks < 4; ++ks)
        qf[ks] = *(const bf16x8*)(Qh + (size_t)(qrow0 + l31) * D_MODEL
                                  + ks * 16 + half * 8);

    bf16x8 ones;
#pragma unroll
    for (int j = 0; j < 8; ++j) ones[j] = (bf16)1.0f;

    f32x16 o[2], lacc;
    int nm = 0;                               // unmasked-key count
#pragma unroll
    for (int i = 0; i < 16; ++i) { o[0][i] = 0.f; o[1][i] = 0.f; lacc[i] = 0.f; }

    // staging geometry: per iter i, wave w covers rows i*32 + w*8 + (lane>>3)
    const int srow = (lane >> 3);            // 0..7
    const int sg   = (lane & 7) ^ srow;      // swizzled global segment

#define STAGE(bb, kt)                                                          \
    do {                                                                       \
        _Pragma("unroll")                                                      \
        for (int i = 0; i < 2; ++i) {                                          \
            int row = i * 32 + wave * 8 + srow;                                \
            ld16(Kh + (size_t)((kt) + row) * D_MODEL + sg * 8,                 \
                 &Klds[bb][i * 2048 + wave * 512]);                            \
            ld16(Vth + (size_t)row * SEQ_L + (kt) + sg * 8,                    \
                 &Vlds[bb][i * 2048 + wave * 512]);                            \
        }                                                                      \
    } while (0)

    // prologue: fill buffer 0
    STAGE(0, 0);
    __syncthreads();

    int cur = 0;
    for (int kt = 0; kt < SEQ_L; kt += 64) {
        // ---- issue next-tile prefetch FIRST (stays in flight under compute)
        if (kt + 64 < SEQ_L) STAGE(cur ^ 1, kt + 64);

        int mv = mask[b * SEQ_L + kt + lane];
        nm += (int)__popcll(__ballot(mv != 0));

        // ---- S^T = K * Q^T : D[key-rows][q-cols]  (Q pre-scaled)
        f32x16 st[2];
#pragma unroll
        for (int ktile = 0; ktile < 2; ++ktile) {
#pragma unroll
            for (int i = 0; i < 16; ++i) st[ktile][i] = 0.f;
#pragma unroll
            for (int ks = 0; ks < 4; ++ks) {
                const int row  = ktile * 32 + l31;
                const int slot = (ks * 2 + half) ^ (l31 & 7);
                bf16x8 kf = *(const bf16x8*)(&Klds[cur][row * 64 + slot * 8]);
                st[ktile] = __builtin_amdgcn_mfma_f32_32x32x16_bf16(
                    kf, qf[ks], st[ktile], 0, 0, 0);
            }
        }

        // ---- P = exp2(S^T); masked keys give st=0 -> p=1 (corrected in l)
        bf16x4 pk[2][4];
#pragma unroll
        for (int ktile = 0; ktile < 2; ++ktile) {
#pragma unroll
            for (int g = 0; g < 4; ++g) {
                bf16x4 pkv;
#pragma unroll
                for (int j = 0; j < 4; ++j)
                    pkv[j] = (bf16)__builtin_amdgcn_exp2f(st[ktile][g * 4 + j]);
                pk[ktile][g] = pkv;
            }
        }

        // ---- C->A layout via one shfl_xor(32) per fragment
        bf16x8 pf[4];
#pragma unroll
        for (int ks = 0; ks < 4; ++ks) {
            const int k1 = ks & 1, kt2 = ks >> 1;
            uint2 a  = __builtin_bit_cast(uint2, pk[kt2][2 * k1]);
            uint2 bb = __builtin_bit_cast(uint2, pk[kt2][2 * k1 + 1]);
            uint2 keep, send;
            keep.x = half ? bb.x : a.x;  keep.y = half ? bb.y : a.y;
            send.x = half ? a.x : bb.x;  send.y = half ? a.y : bb.y;
            uint2 recv;
            recv.x = (unsigned)__shfl_xor((int)send.x, 32);
            recv.y = (unsigned)__shfl_xor((int)send.y, 32);
            uint4 frag;
            frag.x = half ? recv.x : keep.x;
            frag.y = half ? recv.y : keep.y;
            frag.z = half ? keep.x : recv.x;
            frag.w = half ? keep.y : recv.y;
            pf[ks] = __builtin_bit_cast(bf16x8, frag);
        }

        // ---- O += P * V ; l += P * ones (row-sums on the MFMA pipe)
#pragma unroll
        for (int ks = 0; ks < 4; ++ks)
            lacc = __builtin_amdgcn_mfma_f32_32x32x16_bf16(pf[ks], ones, lacc, 0, 0, 0);
#pragma unroll
        for (int dt = 0; dt < 2; ++dt) {
#pragma unroll
            for (int ks = 0; ks < 4; ++ks) {
                const int row  = dt * 32 + l31;
                const int slot = (ks * 2 + half) ^ (l31 & 7);
                bf16x8 vf = *(const bf16x8*)(&Vlds[cur][row * 64 + slot * 8]);
                o[dt] = __builtin_amdgcn_mfma_f32_32x32x16_bf16(
                    pf[ks], vf, o[dt], 0, 0, 0);
            }
        }

        // joins waves AND drains the in-flight prefetch (vmcnt(0) before barrier)
        __syncthreads();
        cur ^= 1;
    }
#undef STAGE

    // ---- epilogue: normalize in-register and write final output.
    //      lacc[r] is column-replicated (B=ones), so every lane holds the
    //      full row-sum for its 16 q-rows; l = lacc - (#masked keys), exact.
    const float corr = (float)(SEQ_L - nm);
#pragma unroll
    for (int r = 0; r < 16; ++r) {
        const int q32 = (r & 3) + 8 * (r >> 2) + 4 * half;
        const int q = qrow0 + q32;
        const size_t base = ((size_t)(b * SEQ_L + q)) * D_MODEL + h * HDIM;
        const float rl = 1.0f / fmaxf(lacc[r] - corr, 1e-30f);
        out[base + l31]      = o[0][r] * rl;
        out[base + 32 + l31] = o[1][r] * rl;
    }
}

extern "C" void kernel_launch(void* const* d_in, const int* in_sizes, int n_in,
                              void* d_out, int out_size, void* d_ws, size_t ws_size,
                              hipStream_t stream) {
    const float* feat = (const float*)d_in[0];
    const int*   mask = (const int*)d_in[1];
    const float* Wq = (const float*)d_in[2];
    const float* bq = (const float*)d_in[3];
    const float* Wk = (const float*)d_in[4];
    const float* bk = (const float*)d_in[5];
    const float* Wv = (const float*)d_in[6];
    const float* bv = (const float*)d_in[7];

    bf16* ws = (bf16*)d_ws;

    convert_in<<<7171, 256, 0, stream>>>(feat, Wq, Wk, Wv, bq, bk, bv, ws);

    dim3 g1(32, 8, 3);
    qkv_gemm<<<g1, 256, 0, stream>>>(ws, ws, mask);

    dim3 g2(2 * NHEAD, SEQ_L / 128);
    attn_kernel<<<g2, 256, 0, stream>>>(ws, mask, (float*)d_out);
}

// Round 8
// 171.620 us; speedup vs baseline: 1.6549x; 1.0174x over previous
//
#include <hip/hip_runtime.h>

typedef __bf16 bf16;
typedef __attribute__((ext_vector_type(4))) __bf16 bf16x4;
typedef __attribute__((ext_vector_type(8))) __bf16 bf16x8;
typedef __attribute__((ext_vector_type(4))) float f32x4;
typedef __attribute__((ext_vector_type(16))) float f32x16;
typedef unsigned int u32;

#define D_MODEL 1024
#define SEQ_L   2048
#define NHEAD   16
#define HDIM    64
#define MROWS   4096   // B*L

// 1/sqrt(64) * log2(e): folded into Wq/bq so attn can use raw v_exp_f32 (exp2)
#define S_SCALE 0.18033688f

// ---- workspace layout (bf16-element offsets) ----
#define FEAT_OFF  512u
#define WQ_OFF    (FEAT_OFF + 4194304u)
#define WK_OFF    (WQ_OFF + 1048576u)
#define WV_OFF    (WK_OFF + 1048576u)
#define BQ_OFF    (WV_OFF + 1048576u)
#define BK_OFF    (BQ_OFF + 1024u)
#define BV_OFF    (BK_OFF + 1024u)
#define Q_OFF     (BV_OFF + 1024u)
#define K_OFF     (Q_OFF + 4194304u)
#define V_OFF     (K_OFF + 4194304u)     // Vt: [b][dout(1024)][token(2048)]

// async global->LDS, 16B per lane; LDS dest = wave-uniform base + lane*16
typedef const __attribute__((address_space(1))) u32* gp_t;
typedef __attribute__((address_space(3))) u32* lp_t;
__device__ __forceinline__ void ld16(const bf16* g, bf16* l) {
    __builtin_amdgcn_global_load_lds((gp_t)g, (lp_t)l, 16, 0, 0);
}

// ---------------------------------------------------------------------------
// Convert f32 inputs -> bf16 in ws. Wq/bq pre-scaled by S_SCALE (exact-count
// rounding: one f32->bf16 round either way). Flat grid: 7171 x 256 x 4.
// ---------------------------------------------------------------------------
__global__ void convert_in(const float* __restrict__ feat,
                           const float* __restrict__ wq, const float* __restrict__ wk,
                           const float* __restrict__ wv,
                           const float* __restrict__ bq, const float* __restrict__ bk,
                           const float* __restrict__ bv,
                           bf16* __restrict__ ws) {
    const int bid = blockIdx.x;
    const float* src; bf16* dst; int off; float sc = 1.0f;
    if (bid < 4096)      { src = feat; dst = ws + FEAT_OFF; off = bid * 1024; }
    else if (bid < 5120) { src = wq;   dst = ws + WQ_OFF;   off = (bid - 4096) * 1024; sc = S_SCALE; }
    else if (bid < 6144) { src = wk;   dst = ws + WK_OFF;   off = (bid - 5120) * 1024; }
    else if (bid < 7168) { src = wv;   dst = ws + WV_OFF;   off = (bid - 6144) * 1024; }
    else if (bid == 7168){ src = bq;   dst = ws + BQ_OFF;   off = 0; sc = S_SCALE; }
    else if (bid == 7169){ src = bk;   dst = ws + BK_OFF;   off = 0; }
    else                 { src = bv;   dst = ws + BV_OFF;   off = 0; }
    int idx = off + threadIdx.x * 4;
    float4 v = *(const float4*)(src + idx);
    bf16x4 o;
    o[0] = (bf16)(v.x * sc);
    o[1] = (bf16)(v.y * sc);
    o[2] = (bf16)(v.z * sc);
    o[3] = (bf16)(v.w * sc);
    *(bf16x4*)(dst + idx) = o;          // one 8B store (coalesced)
}

// ---------------------------------------------------------------------------
// QKV projection v2 — Q and K FUSED (they share the A operand X):
//   zi=0: block stages X-tile ONCE + Wq'-tile + Wk-tile -> computes BOTH
//         Q=X*Wq'^T and K=X*Wk^T 128x128 tiles. Staging bytes/output -25%,
//         MFMA per k-step per wave 32 -> 64 (denser convoy).
//   zi=1: Vt = Wv*X^T transposed (old z=2 path, unchanged math).
// Grid (32,8,2) = 512 blocks = EXACTLY one round at 2 blocks/CU (old 768-
// block grid ran 512+256 with a half-empty tail round).
// LDS pool 48KB shared by both paths. launch_bounds(256,2): VGPR cap 256.
// ---------------------------------------------------------------------------
__global__ __launch_bounds__(256, 2) void qkv_gemm(const bf16* __restrict__ ws,
                                                   bf16* __restrict__ wsw,
                                                   const int* __restrict__ mask) {
    __shared__ bf16 smem[3 * 128 * 64];        // A | B0 | B1 (B1 idle in Vt path)
    bf16* Alds = smem;
    bf16* B0   = smem + 8192;
    bf16* B1   = smem + 16384;

    const int zi   = blockIdx.z;
    const int t    = threadIdx.x;
    const int lane = t & 63;
    const int wave = t >> 6;
    const int quad = lane >> 4;
    const int l16  = lane & 15;
    const int wrow = (wave >> 1) * 64;
    const int wcol = (wave & 1) * 64;
    const int r8 = lane >> 3;
    const int sl = lane & 7;
    const int sg = sl ^ r8;

    if (zi == 0) {
        // ================= fused Q,K =================
        const bf16* X   = ws + FEAT_OFF;
        const bf16* Wq  = ws + WQ_OFF;     // pre-scaled by S_SCALE
        const bf16* Wk  = ws + WK_OFF;
        const int m0 = blockIdx.x * 128;   // token rows
        const int n0 = blockIdx.y * 128;   // output cols

        f32x4 aq[4][4], ak[4][4];
        for (int mi = 0; mi < 4; ++mi)
            for (int ni = 0; ni < 4; ++ni) {
                aq[mi][ni] = (f32x4){0.f, 0.f, 0.f, 0.f};
                ak[mi][ni] = (f32x4){0.f, 0.f, 0.f, 0.f};
            }

        for (int k0 = 0; k0 < D_MODEL; k0 += 64) {
#pragma unroll
            for (int i = 0; i < 4; ++i) {
                int ch  = wave * 4 + i;
                int row = ch * 8 + r8;
                ld16(X  + (size_t)(m0 + row) * D_MODEL + k0 + sg * 8, Alds + ch * 512);
                ld16(Wq + (size_t)(n0 + row) * D_MODEL + k0 + sg * 8, B0   + ch * 512);
                ld16(Wk + (size_t)(n0 + row) * D_MODEL + k0 + sg * 8, B1   + ch * 512);
            }
            __syncthreads();

#pragma unroll
            for (int kk = 0; kk < 2; ++kk) {
                const int sgb = quad + kk * 4;
                bf16x8 af[4];
#pragma unroll
                for (int mi = 0; mi < 4; ++mi) {
                    int row = wrow + mi * 16 + l16;
                    af[mi] = *(const bf16x8*)(&Alds[row * 64 + ((sgb ^ (row & 7)) << 3)]);
                }
                {   // Q: consume B0 fully before touching B1 (register reuse)
                    bf16x8 bfr[4];
#pragma unroll
                    for (int ni = 0; ni < 4; ++ni) {
                        int row = wcol + ni * 16 + l16;
                        bfr[ni] = *(const bf16x8*)(&B0[row * 64 + ((sgb ^ (row & 7)) << 3)]);
                    }
#pragma unroll
                    for (int mi = 0; mi < 4; ++mi)
#pragma unroll
                        for (int ni = 0; ni < 4; ++ni)
                            aq[mi][ni] = __builtin_amdgcn_mfma_f32_16x16x32_bf16(
                                af[mi], bfr[ni], aq[mi][ni], 0, 0, 0);
                }
                {   // K
                    bf16x8 bfr[4];
#pragma unroll
                    for (int ni = 0; ni < 4; ++ni) {
                        int row = wcol + ni * 16 + l16;
                        bfr[ni] = *(const bf16x8*)(&B1[row * 64 + ((sgb ^ (row & 7)) << 3)]);
                    }
#pragma unroll
                    for (int mi = 0; mi < 4; ++mi)
#pragma unroll
                        for (int ni = 0; ni < 4; ++ni)
                            ak[mi][ni] = __builtin_amdgcn_mfma_f32_16x16x32_bf16(
                                af[mi], bfr[ni], ak[mi][ni], 0, 0, 0);
                }
            }
            __syncthreads();
        }

        bf16* Yq = wsw + Q_OFF;
        bf16* Yk = wsw + K_OFF;
        const bf16* bq = ws + BQ_OFF;
        const bf16* bk = ws + BK_OFF;
#pragma unroll
        for (int ni = 0; ni < 4; ++ni) {
            int col = n0 + wcol + ni * 16 + l16;
            float bqf = (float)bq[col];
            float bkf = (float)bk[col];
#pragma unroll
            for (int mi = 0; mi < 4; ++mi) {
                int rowb = m0 + wrow + mi * 16 + quad * 4;
#pragma unroll
                for (int r = 0; r < 4; ++r) {
                    Yq[(size_t)(rowb + r) * D_MODEL + col] = (bf16)(aq[mi][ni][r] + bqf);
                    float v = ak[mi][ni][r] + bkf;
                    if (mask[rowb + r] == 0) v = 0.f;             // zero masked K rows
                    Yk[(size_t)(rowb + r) * D_MODEL + col] = (bf16)v;
                }
            }
        }
    } else {
        // ================= Vt = Wv * X^T (transposed write) =================
        const bf16* Amat = ws + WV_OFF;
        const bf16* Bmat = ws + FEAT_OFF;
        const bf16* bias = ws + BV_OFF;
        bf16* Y = wsw + V_OFF;
        const int m0 = blockIdx.y * 128;   // dout rows (1024 -> 8 tiles)
        const int n0 = blockIdx.x * 128;   // token cols (4096 -> 32 tiles)

        f32x4 acc[4][4];
        for (int mi = 0; mi < 4; ++mi)
            for (int ni = 0; ni < 4; ++ni)
                acc[mi][ni] = (f32x4){0.f, 0.f, 0.f, 0.f};

        for (int k0 = 0; k0 < D_MODEL; k0 += 64) {
#pragma unroll
            for (int i = 0; i < 4; ++i) {
                int ch  = wave * 4 + i;
                int row = ch * 8 + r8;
                ld16(Amat + (size_t)(m0 + row) * D_MODEL + k0 + sg * 8, Alds + ch * 512);
                ld16(Bmat + (size_t)(n0 + row) * D_MODEL + k0 + sg * 8, B0   + ch * 512);
            }
            __syncthreads();

#pragma unroll
            for (int kk = 0; kk < 2; ++kk) {
                const int sgb = quad + kk * 4;
                bf16x8 af[4], bfr[4];
#pragma unroll
                for (int mi = 0; mi < 4; ++mi) {
                    int row = wrow + mi * 16 + l16;
                    af[mi] = *(const bf16x8*)(&Alds[row * 64 + ((sgb ^ (row & 7)) << 3)]);
                }
#pragma unroll
                for (int ni = 0; ni < 4; ++ni) {
                    int row = wcol + ni * 16 + l16;
                    bfr[ni] = *(const bf16x8*)(&B0[row * 64 + ((sgb ^ (row & 7)) << 3)]);
                }
#pragma unroll
                for (int mi = 0; mi < 4; ++mi)
#pragma unroll
                    for (int ni = 0; ni < 4; ++ni)
                        acc[mi][ni] = __builtin_amdgcn_mfma_f32_16x16x32_bf16(
                            af[mi], bfr[ni], acc[mi][ni], 0, 0, 0);
            }
            __syncthreads();
        }

#pragma unroll
        for (int mi = 0; mi < 4; ++mi) {
#pragma unroll
            for (int r = 0; r < 4; ++r) {
                int rowv = m0 + wrow + mi * 16 + quad * 4 + r;   // dout
                float bvf = (float)bias[rowv];
#pragma unroll
                for (int ni = 0; ni < 4; ++ni) {
                    int col = n0 + wcol + ni * 16 + l16;          // token
                    float v = acc[mi][ni][r] + bvf;
                    if (mask[col] == 0) v = 0.f;                  // zero masked Vt cols
                    size_t addr = (size_t)(col >> 11) * 2097152u +
                                  (size_t)rowv * 2048u + (col & 2047);
                    Y[addr] = (bf16)v;
                }
            }
        }
    }
}

// ---------------------------------------------------------------------------
// Flash attention v14 (kept from round 7): v9 structure, no key-split, final
// normalization in-register (no combine kernel). grid (32,16), 256 thr.
// ---------------------------------------------------------------------------
__global__ __launch_bounds__(256, 4) void attn_kernel(
    const bf16* __restrict__ ws,
    const int* __restrict__ mask, float* __restrict__ out) {
    const int bh  = blockIdx.x;          // 0..31
    const int qt  = blockIdx.y;          // 0..15 (128 q-rows per block)
    const int b   = bh >> 4, h = bh & 15;
    const int t    = threadIdx.x;
    const int lane = t & 63;
    const int wave = t >> 6;            // 0..3
    const int half = lane >> 5;
    const int l31  = lane & 31;

    __shared__ bf16 Klds[2][64 * 64];         // [buf][key][d], seg-swizzled
    __shared__ bf16 Vlds[2][64 * 64];         // [buf][d][key], seg-swizzled

    const bf16* Qh  = ws + Q_OFF + (size_t)(b * SEQ_L) * D_MODEL + h * HDIM;
    const bf16* Kh  = ws + K_OFF + (size_t)(b * SEQ_L) * D_MODEL + h * HDIM;
    const bf16* Vth = ws + V_OFF + (size_t)b * 2097152u + (size_t)(h * HDIM) * SEQ_L;

    // Q fragments as B-operand (n=q=l31, k=d); scale already folded into Wq.
    const int qrow0 = qt * 128 + wave * 32;
    bf16x8 qf[4];
#pragma unroll
    for (int ks = 0; ks < 4; ++ks)
        qf[ks] = *(const bf16x8*)(Qh + (size_t)(qrow0 + l31) * D_MODEL
                                  + ks * 16 + half * 8);

    bf16x8 ones;
#pragma unroll
    for (int j = 0; j < 8; ++j) ones[j] = (bf16)1.0f;

    f32x16 o[2], lacc;
    int nm = 0;                               // unmasked-key count
#pragma unroll
    for (int i = 0; i < 16; ++i) { o[0][i] = 0.f; o[1][i] = 0.f; lacc[i] = 0.f; }

    // staging geometry: per iter i, wave w covers rows i*32 + w*8 + (lane>>3)
    const int srow = (lane >> 3);            // 0..7
    const int sg   = (lane & 7) ^ srow;      // swizzled global segment

#define STAGE(bb, kt)                                                          \
    do {                                                                       \
        _Pragma("unroll")                                                      \
        for (int i = 0; i < 2; ++i) {                                          \
            int row = i * 32 + wave * 8 + srow;                                \
            ld16(Kh + (size_t)((kt) + row) * D_MODEL + sg * 8,                 \
                 &Klds[bb][i * 2048 + wave * 512]);                            \
            ld16(Vth + (size_t)row * SEQ_L + (kt) + sg * 8,                    \
                 &Vlds[bb][i * 2048 + wave * 512]);                            \
        }                                                                      \
    } while (0)

    // prologue: fill buffer 0
    STAGE(0, 0);
    __syncthreads();

    int cur = 0;
    for (int kt = 0; kt < SEQ_L; kt += 64) {
        // ---- issue next-tile prefetch FIRST (stays in flight under compute)
        if (kt + 64 < SEQ_L) STAGE(cur ^ 1, kt + 64);

        int mv = mask[b * SEQ_L + kt + lane];
        nm += (int)__popcll(__ballot(mv != 0));

        // ---- S^T = K * Q^T : D[key-rows][q-cols]  (Q pre-scaled)
        f32x16 st[2];
#pragma unroll
        for (int ktile = 0; ktile < 2; ++ktile) {
#pragma unroll
            for (int i = 0; i < 16; ++i) st[ktile][i] = 0.f;
#pragma unroll
            for (int ks = 0; ks < 4; ++ks) {
                const int row  = ktile * 32 + l31;
                const int slot = (ks * 2 + half) ^ (l31 & 7);
                bf16x8 kf = *(const bf16x8*)(&Klds[cur][row * 64 + slot * 8]);
                st[ktile] = __builtin_amdgcn_mfma_f32_32x32x16_bf16(
                    kf, qf[ks], st[ktile], 0, 0, 0);
            }
        }

        // ---- P = exp2(S^T); masked keys give st=0 -> p=1 (corrected in l)
        bf16x4 pk[2][4];
#pragma unroll
        for (int ktile = 0; ktile < 2; ++ktile) {
#pragma unroll
            for (int g = 0; g < 4; ++g) {
                bf16x4 pkv;
#pragma unroll
                for (int j = 0; j < 4; ++j)
                    pkv[j] = (bf16)__builtin_amdgcn_exp2f(st[ktile][g * 4 + j]);
                pk[ktile][g] = pkv;
            }
        }

        // ---- C->A layout via one shfl_xor(32) per fragment
        bf16x8 pf[4];
#pragma unroll
        for (int ks = 0; ks < 4; ++ks) {
            const int k1 = ks & 1, kt2 = ks >> 1;
            uint2 a  = __builtin_bit_cast(uint2, pk[kt2][2 * k1]);
            uint2 bb = __builtin_bit_cast(uint2, pk[kt2][2 * k1 + 1]);
            uint2 keep, send;
            keep.x = half ? bb.x : a.x;  keep.y = half ? bb.y : a.y;
            send.x = half ? a.x : bb.x;  send.y = half ? a.y : bb.y;
            uint2 recv;
            recv.x = (unsigned)__shfl_xor((int)send.x, 32);
            recv.y = (unsigned)__shfl_xor((int)send.y, 32);
            uint4 frag;
            frag.x = half ? recv.x : keep.x;
            frag.y = half ? recv.y : keep.y;
            frag.z = half ? keep.x : recv.x;
            frag.w = half ? keep.y : recv.y;
            pf[ks] = __builtin_bit_cast(bf16x8, frag);
        }

        // ---- O += P * V ; l += P * ones (row-sums on the MFMA pipe)
#pragma unroll
        for (int ks = 0; ks < 4; ++ks)
            lacc = __builtin_amdgcn_mfma_f32_32x32x16_bf16(pf[ks], ones, lacc, 0, 0, 0);
#pragma unroll
        for (int dt = 0; dt < 2; ++dt) {
#pragma unroll
            for (int ks = 0; ks < 4; ++ks) {
                const int row  = dt * 32 + l31;
                const int slot = (ks * 2 + half) ^ (l31 & 7);
                bf16x8 vf = *(const bf16x8*)(&Vlds[cur][row * 64 + slot * 8]);
                o[dt] = __builtin_amdgcn_mfma_f32_32x32x16_bf16(
                    pf[ks], vf, o[dt], 0, 0, 0);
            }
        }

        // joins waves AND drains the in-flight prefetch (vmcnt(0) before barrier)
        __syncthreads();
        cur ^= 1;
    }
#undef STAGE

    // ---- epilogue: normalize in-register and write final output.
    const float corr = (float)(SEQ_L - nm);
#pragma unroll
    for (int r = 0; r < 16; ++r) {
        const int q32 = (r & 3) + 8 * (r >> 2) + 4 * half;
        const int q = qrow0 + q32;
        const size_t base = ((size_t)(b * SEQ_L + q)) * D_MODEL + h * HDIM;
        const float rl = 1.0f / fmaxf(lacc[r] - corr, 1e-30f);
        out[base + l31]      = o[0][r] * rl;
        out[base + 32 + l31] = o[1][r] * rl;
    }
}

extern "C" void kernel_launch(void* const* d_in, const int* in_sizes, int n_in,
                              void* d_out, int out_size, void* d_ws, size_t ws_size,
                              hipStream_t stream) {
    const float* feat = (const float*)d_in[0];
    const int*   mask = (const int*)d_in[1];
    const float* Wq = (const float*)d_in[2];
    const float* bq = (const float*)d_in[3];
    const float* Wk = (const float*)d_in[4];
    const float* bk = (const float*)d_in[5];
    const float* Wv = (const float*)d_in[6];
    const float* bv = (const float*)d_in[7];

    bf16* ws = (bf16*)d_ws;

    convert_in<<<7171, 256, 0, stream>>>(feat, Wq, Wk, Wv, bq, bk, bv, ws);

    dim3 g1(32, 8, 2);
    qkv_gemm<<<g1, 256, 0, stream>>>(ws, ws, mask);

    dim3 g2(2 * NHEAD, SEQ_L / 128);
    attn_kernel<<<g2, 256, 0, stream>>>(ws, mask, (float*)d_out);
}

// Round 9
// 161.209 us; speedup vs baseline: 1.7618x; 1.0646x over previous
//
#include <hip/hip_runtime.h>

typedef __bf16 bf16;
typedef __attribute__((ext_vector_type(4))) __bf16 bf16x4;
typedef __attribute__((ext_vector_type(8))) __bf16 bf16x8;
typedef __attribute__((ext_vector_type(4))) float f32x4;
typedef __attribute__((ext_vector_type(16))) float f32x16;
typedef unsigned int u32;

#define D_MODEL 1024
#define SEQ_L   2048
#define NHEAD   16
#define HDIM    64
#define MROWS   4096   // B*L

// 1/sqrt(64) * log2(e): folded into Wq/bq so attn can use raw v_exp_f32 (exp2)
#define S_SCALE 0.18033688f

// ---- workspace layout (bf16-element offsets) ----
#define FEAT_OFF  512u
#define WQ_OFF    (FEAT_OFF + 4194304u)
#define WK_OFF    (WQ_OFF + 1048576u)
#define WV_OFF    (WK_OFF + 1048576u)
#define BQ_OFF    (WV_OFF + 1048576u)
#define BK_OFF    (BQ_OFF + 1024u)
#define BV_OFF    (BK_OFF + 1024u)
#define Q_OFF     (BV_OFF + 1024u)
#define K_OFF     (Q_OFF + 4194304u)
#define V_OFF     (K_OFF + 4194304u)     // Vt: [b][dout(1024)][token(2048)]

// async global->LDS, 16B per lane; LDS dest = wave-uniform base + lane*16
typedef const __attribute__((address_space(1))) u32* gp_t;
typedef __attribute__((address_space(3))) u32* lp_t;
__device__ __forceinline__ void ld16(const bf16* g, bf16* l) {
    __builtin_amdgcn_global_load_lds((gp_t)g, (lp_t)l, 16, 0, 0);
}

// ---------------------------------------------------------------------------
// Convert f32 inputs -> bf16 in ws. Wq/bq pre-scaled by S_SCALE (exact-count
// rounding: one f32->bf16 round either way). Flat grid: 7171 x 256 x 4.
// ---------------------------------------------------------------------------
__global__ void convert_in(const float* __restrict__ feat,
                           const float* __restrict__ wq, const float* __restrict__ wk,
                           const float* __restrict__ wv,
                           const float* __restrict__ bq, const float* __restrict__ bk,
                           const float* __restrict__ bv,
                           bf16* __restrict__ ws) {
    const int bid = blockIdx.x;
    const float* src; bf16* dst; int off; float sc = 1.0f;
    if (bid < 4096)      { src = feat; dst = ws + FEAT_OFF; off = bid * 1024; }
    else if (bid < 5120) { src = wq;   dst = ws + WQ_OFF;   off = (bid - 4096) * 1024; sc = S_SCALE; }
    else if (bid < 6144) { src = wk;   dst = ws + WK_OFF;   off = (bid - 5120) * 1024; }
    else if (bid < 7168) { src = wv;   dst = ws + WV_OFF;   off = (bid - 6144) * 1024; }
    else if (bid == 7168){ src = bq;   dst = ws + BQ_OFF;   off = 0; sc = S_SCALE; }
    else if (bid == 7169){ src = bk;   dst = ws + BK_OFF;   off = 0; }
    else                 { src = bv;   dst = ws + BV_OFF;   off = 0; }
    int idx = off + threadIdx.x * 4;
    float4 v = *(const float4*)(src + idx);
    bf16x4 o;
    o[0] = (bf16)(v.x * sc);
    o[1] = (bf16)(v.y * sc);
    o[2] = (bf16)(v.z * sc);
    o[3] = (bf16)(v.w * sc);
    *(bf16x4*)(dst + idx) = o;          // one 8B store (coalesced)
}

// ---------------------------------------------------------------------------
// QKV projection v2 (round-8 win, kept): Q and K fused (shared X staging);
// zi=1: Vt = Wv*X^T transposed. Grid (32,8,2) = 512 blocks, one full round.
// ---------------------------------------------------------------------------
__global__ __launch_bounds__(256, 2) void qkv_gemm(const bf16* __restrict__ ws,
                                                   bf16* __restrict__ wsw,
                                                   const int* __restrict__ mask) {
    __shared__ bf16 smem[3 * 128 * 64];        // A | B0 | B1 (B1 idle in Vt path)
    bf16* Alds = smem;
    bf16* B0   = smem + 8192;
    bf16* B1   = smem + 16384;

    const int zi   = blockIdx.z;
    const int t    = threadIdx.x;
    const int lane = t & 63;
    const int wave = t >> 6;
    const int quad = lane >> 4;
    const int l16  = lane & 15;
    const int wrow = (wave >> 1) * 64;
    const int wcol = (wave & 1) * 64;
    const int r8 = lane >> 3;
    const int sl = lane & 7;
    const int sg = sl ^ r8;

    if (zi == 0) {
        // ================= fused Q,K =================
        const bf16* X   = ws + FEAT_OFF;
        const bf16* Wq  = ws + WQ_OFF;     // pre-scaled by S_SCALE
        const bf16* Wk  = ws + WK_OFF;
        const int m0 = blockIdx.x * 128;   // token rows
        const int n0 = blockIdx.y * 128;   // output cols

        f32x4 aq[4][4], ak[4][4];
        for (int mi = 0; mi < 4; ++mi)
            for (int ni = 0; ni < 4; ++ni) {
                aq[mi][ni] = (f32x4){0.f, 0.f, 0.f, 0.f};
                ak[mi][ni] = (f32x4){0.f, 0.f, 0.f, 0.f};
            }

        for (int k0 = 0; k0 < D_MODEL; k0 += 64) {
#pragma unroll
            for (int i = 0; i < 4; ++i) {
                int ch  = wave * 4 + i;
                int row = ch * 8 + r8;
                ld16(X  + (size_t)(m0 + row) * D_MODEL + k0 + sg * 8, Alds + ch * 512);
                ld16(Wq + (size_t)(n0 + row) * D_MODEL + k0 + sg * 8, B0   + ch * 512);
                ld16(Wk + (size_t)(n0 + row) * D_MODEL + k0 + sg * 8, B1   + ch * 512);
            }
            __syncthreads();

#pragma unroll
            for (int kk = 0; kk < 2; ++kk) {
                const int sgb = quad + kk * 4;
                bf16x8 af[4];
#pragma unroll
                for (int mi = 0; mi < 4; ++mi) {
                    int row = wrow + mi * 16 + l16;
                    af[mi] = *(const bf16x8*)(&Alds[row * 64 + ((sgb ^ (row & 7)) << 3)]);
                }
                {   // Q
                    bf16x8 bfr[4];
#pragma unroll
                    for (int ni = 0; ni < 4; ++ni) {
                        int row = wcol + ni * 16 + l16;
                        bfr[ni] = *(const bf16x8*)(&B0[row * 64 + ((sgb ^ (row & 7)) << 3)]);
                    }
#pragma unroll
                    for (int mi = 0; mi < 4; ++mi)
#pragma unroll
                        for (int ni = 0; ni < 4; ++ni)
                            aq[mi][ni] = __builtin_amdgcn_mfma_f32_16x16x32_bf16(
                                af[mi], bfr[ni], aq[mi][ni], 0, 0, 0);
                }
                {   // K
                    bf16x8 bfr[4];
#pragma unroll
                    for (int ni = 0; ni < 4; ++ni) {
                        int row = wcol + ni * 16 + l16;
                        bfr[ni] = *(const bf16x8*)(&B1[row * 64 + ((sgb ^ (row & 7)) << 3)]);
                    }
#pragma unroll
                    for (int mi = 0; mi < 4; ++mi)
#pragma unroll
                        for (int ni = 0; ni < 4; ++ni)
                            ak[mi][ni] = __builtin_amdgcn_mfma_f32_16x16x32_bf16(
                                af[mi], bfr[ni], ak[mi][ni], 0, 0, 0);
                }
            }
            __syncthreads();
        }

        bf16* Yq = wsw + Q_OFF;
        bf16* Yk = wsw + K_OFF;
        const bf16* bq = ws + BQ_OFF;
        const bf16* bk = ws + BK_OFF;
#pragma unroll
        for (int ni = 0; ni < 4; ++ni) {
            int col = n0 + wcol + ni * 16 + l16;
            float bqf = (float)bq[col];
            float bkf = (float)bk[col];
#pragma unroll
            for (int mi = 0; mi < 4; ++mi) {
                int rowb = m0 + wrow + mi * 16 + quad * 4;
#pragma unroll
                for (int r = 0; r < 4; ++r) {
                    Yq[(size_t)(rowb + r) * D_MODEL + col] = (bf16)(aq[mi][ni][r] + bqf);
                    float v = ak[mi][ni][r] + bkf;
                    if (mask[rowb + r] == 0) v = 0.f;             // zero masked K rows
                    Yk[(size_t)(rowb + r) * D_MODEL + col] = (bf16)v;
                }
            }
        }
    } else {
        // ================= Vt = Wv * X^T (transposed write) =================
        const bf16* Amat = ws + WV_OFF;
        const bf16* Bmat = ws + FEAT_OFF;
        const bf16* bias = ws + BV_OFF;
        bf16* Y = wsw + V_OFF;
        const int m0 = blockIdx.y * 128;   // dout rows
        const int n0 = blockIdx.x * 128;   // token cols

        f32x4 acc[4][4];
        for (int mi = 0; mi < 4; ++mi)
            for (int ni = 0; ni < 4; ++ni)
                acc[mi][ni] = (f32x4){0.f, 0.f, 0.f, 0.f};

        for (int k0 = 0; k0 < D_MODEL; k0 += 64) {
#pragma unroll
            for (int i = 0; i < 4; ++i) {
                int ch  = wave * 4 + i;
                int row = ch * 8 + r8;
                ld16(Amat + (size_t)(m0 + row) * D_MODEL + k0 + sg * 8, Alds + ch * 512);
                ld16(Bmat + (size_t)(n0 + row) * D_MODEL + k0 + sg * 8, B0   + ch * 512);
            }
            __syncthreads();

#pragma unroll
            for (int kk = 0; kk < 2; ++kk) {
                const int sgb = quad + kk * 4;
                bf16x8 af[4], bfr[4];
#pragma unroll
                for (int mi = 0; mi < 4; ++mi) {
                    int row = wrow + mi * 16 + l16;
                    af[mi] = *(const bf16x8*)(&Alds[row * 64 + ((sgb ^ (row & 7)) << 3)]);
                }
#pragma unroll
                for (int ni = 0; ni < 4; ++ni) {
                    int row = wcol + ni * 16 + l16;
                    bfr[ni] = *(const bf16x8*)(&B0[row * 64 + ((sgb ^ (row & 7)) << 3)]);
                }
#pragma unroll
                for (int mi = 0; mi < 4; ++mi)
#pragma unroll
                    for (int ni = 0; ni < 4; ++ni)
                        acc[mi][ni] = __builtin_amdgcn_mfma_f32_16x16x32_bf16(
                            af[mi], bfr[ni], acc[mi][ni], 0, 0, 0);
            }
            __syncthreads();
        }

#pragma unroll
        for (int mi = 0; mi < 4; ++mi) {
#pragma unroll
            for (int r = 0; r < 4; ++r) {
                int rowv = m0 + wrow + mi * 16 + quad * 4 + r;   // dout
                float bvf = (float)bias[rowv];
#pragma unroll
                for (int ni = 0; ni < 4; ++ni) {
                    int col = n0 + wcol + ni * 16 + l16;          // token
                    float v = acc[mi][ni][r] + bvf;
                    if (mask[col] == 0) v = 0.f;                  // zero masked Vt cols
                    size_t addr = (size_t)(col >> 11) * 2097152u +
                                  (size_t)rowv * 2048u + (col & 2047);
                    Y[addr] = (bf16)v;
                }
            }
        }
    }
}

// ---------------------------------------------------------------------------
// Flash attention v15 = two v9-blocks fused into one 512-thread block with an
// IN-BLOCK key-split. Waves: qh = wave&3 (32 q-rows each), kh = wave>>2 (key
// half [kh*1024, kh*1024+1024)). Each 4-wave kh-group runs v9's exact
// KVBLK=64 double-buffered pipeline (16 iters, same staging/swizzles/MFMA).
// LDS 64KB (2 kh x 32KB) -> 2 blocks/CU x 8 waves = 16 waves/CU (v9's
// measured-best occupancy: 50.4us vs 60.5 at 8 waves/CU) WITHOUT the combine
// kernel: cross-half reduction happens in the dead K/V LDS after the loop.
// grid (bh, qt) = (32, 16) = 512 blocks = exactly 2/CU.
// ---------------------------------------------------------------------------
__global__ __launch_bounds__(512, 4) void attn_kernel(
    const bf16* __restrict__ ws,
    const int* __restrict__ mask, float* __restrict__ out) {
    const int bh  = blockIdx.x;          // 0..31
    const int qt  = blockIdx.y;          // 0..15 (128 q-rows per block)
    const int b   = bh >> 4, h = bh & 15;
    const int t    = threadIdx.x;
    const int lane = t & 63;
    const int wave = t >> 6;            // 0..7
    const int qh   = wave & 3;          // q sub-tile within block
    const int kh   = wave >> 2;         // key half
    const int half = lane >> 5;
    const int l31  = lane & 31;
    const int kt0  = kh * 1024;

    __shared__ bf16 smem[32768];        // 64KB: K[kh][buf][4096] | V[kh][buf][4096]
    bf16* Kb = smem;                    // K(kh,buf) = Kb + (kh*2+buf)*4096
    bf16* Vb = smem + 16384;            // V(kh,buf) = Vb + (kh*2+buf)*4096

    const bf16* Qh  = ws + Q_OFF + (size_t)(b * SEQ_L) * D_MODEL + h * HDIM;
    const bf16* Kh  = ws + K_OFF + (size_t)(b * SEQ_L) * D_MODEL + h * HDIM;
    const bf16* Vth = ws + V_OFF + (size_t)b * 2097152u + (size_t)(h * HDIM) * SEQ_L;

    // Q fragments as B-operand (n=q=l31, k=d); scale already folded into Wq.
    const int qrow0 = qt * 128 + qh * 32;
    bf16x8 qf[4];
#pragma unroll
    for (int ks = 0; ks < 4; ++ks)
        qf[ks] = *(const bf16x8*)(Qh + (size_t)(qrow0 + l31) * D_MODEL
                                  + ks * 16 + half * 8);

    bf16x8 ones;
#pragma unroll
    for (int j = 0; j < 8; ++j) ones[j] = (bf16)1.0f;

    f32x16 o[2], lacc;
    int nm = 0;                               // unmasked keys in THIS half
#pragma unroll
    for (int i = 0; i < 16; ++i) { o[0][i] = 0.f; o[1][i] = 0.f; lacc[i] = 0.f; }

    // staging geometry (v9, with qh playing v9's wave role inside the kh-group)
    const int srow = (lane >> 3);            // 0..7
    const int sg   = (lane & 7) ^ srow;      // swizzled global segment

#define STAGE(bb, kt)                                                          \
    do {                                                                       \
        _Pragma("unroll")                                                      \
        for (int i = 0; i < 2; ++i) {                                          \
            int row = i * 32 + qh * 8 + srow;                                  \
            ld16(Kh + (size_t)((kt) + row) * D_MODEL + sg * 8,                 \
                 Kb + (kh * 2 + (bb)) * 4096 + i * 2048 + qh * 512);           \
            ld16(Vth + (size_t)row * SEQ_L + (kt) + sg * 8,                    \
                 Vb + (kh * 2 + (bb)) * 4096 + i * 2048 + qh * 512);           \
        }                                                                      \
    } while (0)

    // prologue: each kh-group fills its buffer 0
    STAGE(0, kt0);
    __syncthreads();

    int cur = 0;
    for (int it = 0; it < 16; ++it) {
        const int kt = kt0 + it * 64;
        // ---- issue next-tile prefetch FIRST (stays in flight under compute)
        if (it < 15) STAGE(cur ^ 1, kt + 64);

        int mv = mask[b * SEQ_L + kt + lane];
        nm += (int)__popcll(__ballot(mv != 0));

        // ---- S^T = K * Q^T : D[key-rows][q-cols]  (Q pre-scaled)
        const bf16* Kcur = Kb + (kh * 2 + cur) * 4096;
        f32x16 st[2];
#pragma unroll
        for (int ktile = 0; ktile < 2; ++ktile) {
#pragma unroll
            for (int i = 0; i < 16; ++i) st[ktile][i] = 0.f;
#pragma unroll
            for (int ks = 0; ks < 4; ++ks) {
                const int row  = ktile * 32 + l31;
                const int slot = (ks * 2 + half) ^ (l31 & 7);
                bf16x8 kf = *(const bf16x8*)(&Kcur[row * 64 + slot * 8]);
                st[ktile] = __builtin_amdgcn_mfma_f32_32x32x16_bf16(
                    kf, qf[ks], st[ktile], 0, 0, 0);
            }
        }

        // ---- P = exp2(S^T); masked keys give st=0 -> p=1 (corrected in l)
        bf16x4 pk[2][4];
#pragma unroll
        for (int ktile = 0; ktile < 2; ++ktile) {
#pragma unroll
            for (int g = 0; g < 4; ++g) {
                bf16x4 pkv;
#pragma unroll
                for (int j = 0; j < 4; ++j)
                    pkv[j] = (bf16)__builtin_amdgcn_exp2f(st[ktile][g * 4 + j]);
                pk[ktile][g] = pkv;
            }
        }

        // ---- C->A layout via one shfl_xor(32) per fragment
        bf16x8 pf[4];
#pragma unroll
        for (int ks = 0; ks < 4; ++ks) {
            const int k1 = ks & 1, kt2 = ks >> 1;
            uint2 a  = __builtin_bit_cast(uint2, pk[kt2][2 * k1]);
            uint2 bb = __builtin_bit_cast(uint2, pk[kt2][2 * k1 + 1]);
            uint2 keep, send;
            keep.x = half ? bb.x : a.x;  keep.y = half ? bb.y : a.y;
            send.x = half ? a.x : bb.x;  send.y = half ? a.y : bb.y;
            uint2 recv;
            recv.x = (unsigned)__shfl_xor((int)send.x, 32);
            recv.y = (unsigned)__shfl_xor((int)send.y, 32);
            uint4 frag;
            frag.x = half ? recv.x : keep.x;
            frag.y = half ? recv.y : keep.y;
            frag.z = half ? keep.x : recv.x;
            frag.w = half ? keep.y : recv.y;
            pf[ks] = __builtin_bit_cast(bf16x8, frag);
        }

        // ---- O += P * V ; l += P * ones (row-sums on the MFMA pipe)
        const bf16* Vcur = Vb + (kh * 2 + cur) * 4096;
#pragma unroll
        for (int ks = 0; ks < 4; ++ks)
            lacc = __builtin_amdgcn_mfma_f32_32x32x16_bf16(pf[ks], ones, lacc, 0, 0, 0);
#pragma unroll
        for (int dt = 0; dt < 2; ++dt) {
#pragma unroll
            for (int ks = 0; ks < 4; ++ks) {
                const int row  = dt * 32 + l31;
                const int slot = (ks * 2 + half) ^ (l31 & 7);
                bf16x8 vf = *(const bf16x8*)(&Vcur[row * 64 + slot * 8]);
                o[dt] = __builtin_amdgcn_mfma_f32_32x32x16_bf16(
                    pf[ks], vf, o[dt], 0, 0, 0);
            }
        }

        // joins waves AND drains the in-flight prefetch (vmcnt(0) before barrier)
        __syncthreads();
        cur ^= 1;
    }
#undef STAGE

    // ---- in-block cross-half reduction (replaces the combine kernel).
    //      K/V buffers are dead after the loop's final barrier; reuse as a
    //      [48][256] f32 exchange (lanes contiguous -> conflict-free).
    const float corr = (float)(1024 - nm);
    float* ex = (float*)smem;
    const int slot = qh * 64 + lane;
    if (kh == 1) {
#pragma unroll
        for (int r = 0; r < 16; ++r) {
            ex[r * 256 + slot]        = o[0][r];
            ex[(16 + r) * 256 + slot] = o[1][r];
            ex[(32 + r) * 256 + slot] = lacc[r] - corr;   // l-partial, corr folded
        }
    }
    __syncthreads();
    if (kh == 0) {
#pragma unroll
        for (int r = 0; r < 16; ++r) {
            const int q32 = (r & 3) + 8 * (r >> 2) + 4 * half;
            const int q = qrow0 + q32;
            const size_t base = ((size_t)(b * SEQ_L + q)) * D_MODEL + h * HDIM;
            const float l  = (lacc[r] - corr) + ex[(32 + r) * 256 + slot];
            const float rl = 1.0f / fmaxf(l, 1e-30f);
            out[base + l31]      = (o[0][r] + ex[r * 256 + slot]) * rl;
            out[base + 32 + l31] = (o[1][r] + ex[(16 + r) * 256 + slot]) * rl;
        }
    }
}

extern "C" void kernel_launch(void* const* d_in, const int* in_sizes, int n_in,
                              void* d_out, int out_size, void* d_ws, size_t ws_size,
                              hipStream_t stream) {
    const float* feat = (const float*)d_in[0];
    const int*   mask = (const int*)d_in[1];
    const float* Wq = (const float*)d_in[2];
    const float* bq = (const float*)d_in[3];
    const float* Wk = (const float*)d_in[4];
    const float* bk = (const float*)d_in[5];
    const float* Wv = (const float*)d_in[6];
    const float* bv = (const float*)d_in[7];

    bf16* ws = (bf16*)d_ws;

    convert_in<<<7171, 256, 0, stream>>>(feat, Wq, Wk, Wv, bq, bk, bv, ws);

    dim3 g1(32, 8, 2);
    qkv_gemm<<<g1, 256, 0, stream>>>(ws, ws, mask);

    dim3 g2(2 * NHEAD, SEQ_L / 128);
    attn_kernel<<<g2, 512, 0, stream>>>(ws, mask, (float*)d_out);
}